// Round 12
// baseline (974.197 us; speedup 1.0000x reference)
//
#include <hip/hip_runtime.h>
#include <hip/hip_bf16.h>
#include <cstdint>
#include <cstddef>

// ---------------------------------------------------------------------------
// Model constants
// ---------------------------------------------------------------------------
#define BT        16384          // B*T tokens
#define MAXASSIGN 33792          // 32768 + 8*127 rounded to 128-aligned segments
#define QSCALE    0.36067376022224085f   // 0.25 * log2(e): fold 1/sqrt(dh) + exp->exp2

typedef __attribute__((ext_vector_type(8)))  short short8;   // 8 bf16 = 1 MFMA frag
typedef __attribute__((ext_vector_type(4)))  short short4v;
typedef __attribute__((ext_vector_type(4)))  float f32x4;
typedef __attribute__((ext_vector_type(16))) float f32x16;

// gelu(x) = 0.5x(1+tanh(u)) = x*sigmoid(2u), u = sqrt(2/pi)(x+0.044715x^3).
__device__ __forceinline__ float gelu_f(float x) {
    float u2l = (x + 0.044715f * x * x * x) * 2.3022081927f;   // 2u*log2(e)
    float e = exp2f(u2l);
    float r = __builtin_amdgcn_rcpf(e + 1.0f);
    return x * e * r;
}

// ---------------------------------------------------------------------------
// 1. x [32,55,512,8] -> xtb [16384][448] bf16 (cols 440..447 zero-padded)
// ---------------------------------------------------------------------------
__global__ __launch_bounds__(256) void transpose_kernel(const float* __restrict__ x,
                                                        __hip_bfloat16* __restrict__ xtb) {
    int idx = blockIdx.x * 256 + threadIdx.x;      // 16384*448 threads exact
    int j   = idx % 448;
    int row = idx / 448;
    int t   = row & 511;
    int b   = row >> 9;
    float v = 0.f;
    if (j < 440) {
        int nb = j >> 3, nc = j & 7;
        v = x[(((size_t)(b * 55 + nb)) * 512 + t) * 8 + nc];
    }
    xtb[idx] = __float2bfloat16(v);
}

// ---------------------------------------------------------------------------
// 2. Weight convert+transpose: out[b][n][k] = bf16(in[b][k][n])
// ---------------------------------------------------------------------------
__global__ __launch_bounds__(256) void wconv_kernel(const float* __restrict__ in,
                                                    __hip_bfloat16* __restrict__ out,
                                                    int K, int N, int total) {
    int idx = blockIdx.x * 256 + threadIdx.x;
    if (idx >= total) return;
    int k = idx % K; int rem = idx / K; int n = rem % N; int b = rem / N;
    out[idx] = __float2bfloat16(in[((size_t)b * K + k) * N + n]);
}

// proj_W [440][128] -> projWt [128][448] bf16 with zero pad k>=440
__global__ __launch_bounds__(256) void projconv_kernel(const float* __restrict__ in,
                                                       __hip_bfloat16* __restrict__ out) {
    int idx = blockIdx.x * 256 + threadIdx.x;      // 128*448 exact
    int k = idx % 448, n = idx / 448;
    out[idx] = __float2bfloat16(k < 440 ? in[k * 128 + n] : 0.f);
}

// ---------------------------------------------------------------------------
// 3. bf16 MFMA GEMM (dense paths only): C = A @ Wt^T (+ epilogue)
//    128x128 tile, BK=64, 256 threads, mfma_f32_16x16x32_bf16, XOR swizzle.
//    mode 0: +bias +pos  | mode 2: +bias +resid | mode 5: bf16, Q pre-scaled
// ---------------------------------------------------------------------------
__global__ __launch_bounds__(256) void mm_kernel(
    const __hip_bfloat16* __restrict__ A, const __hip_bfloat16* __restrict__ Wt,
    const float* __restrict__ bias, const float* __restrict__ extra,
    void* __restrict__ Cout, int K, int N, int mode)
{
    __shared__ short As[128 * 64];   // 16 KB, chunk-swizzled [row][c^(row&7)]
    __shared__ short Bs[128 * 64];   // 16 KB
    const int tid  = threadIdx.x;
    const int row0 = blockIdx.x * 128;
    const int col0 = blockIdx.y * 128;

    const int crow = tid >> 3;   // 0..31
    const int cc   = tid & 7;    // 0..7

    f32x4 acc[4][4];
#pragma unroll
    for (int i = 0; i < 4; ++i)
#pragma unroll
        for (int j = 0; j < 4; ++j) acc[i][j] = (f32x4){0.f, 0.f, 0.f, 0.f};

    const int wave = tid >> 6, lane = tid & 63;
    const int wm = (wave >> 1) * 64, wn = (wave & 1) * 64;
    const int lr = lane & 15, q = lane >> 4;

    for (int k0 = 0; k0 < K; k0 += 64) {
#pragma unroll
        for (int p = 0; p < 4; ++p) {
            int row = p * 32 + crow;
            uint4 va = *(const uint4*)(A + (size_t)(row0 + row) * K + k0 + cc * 8);
            *(uint4*)&As[(row * 8 + (cc ^ (row & 7))) * 8] = va;
            uint4 vb = *(const uint4*)(Wt + (size_t)(col0 + row) * K + k0 + cc * 8);
            *(uint4*)&Bs[(row * 8 + (cc ^ (row & 7))) * 8] = vb;
        }
        __syncthreads();
#pragma unroll
        for (int s = 0; s < 2; ++s) {
            short8 af[4], bf[4];
#pragma unroll
            for (int f = 0; f < 4; ++f) {
                int m = wm + f * 16 + lr;
                af[f] = *(const short8*)&As[(m * 8 + ((s * 4 + q) ^ (m & 7))) * 8];
                int n = wn + f * 16 + lr;
                bf[f] = *(const short8*)&Bs[(n * 8 + ((s * 4 + q) ^ (n & 7))) * 8];
            }
#pragma unroll
            for (int i = 0; i < 4; ++i)
#pragma unroll
                for (int j = 0; j < 4; ++j)
                    acc[i][j] = __builtin_amdgcn_mfma_f32_16x16x32_bf16(
                        af[i], bf[j], acc[i][j], 0, 0, 0);
        }
        __syncthreads();
    }

    float bcol[4];
#pragma unroll
    for (int j = 0; j < 4; ++j) bcol[j] = bias[col0 + wn + j * 16 + lr];
#pragma unroll
    for (int i = 0; i < 4; ++i) {
#pragma unroll
        for (int r = 0; r < 4; ++r) {
            int grow = row0 + wm + i * 16 + q * 4 + r;
#pragma unroll
            for (int j = 0; j < 4; ++j) {
                int gcol = col0 + wn + j * 16 + lr;
                float v = acc[i][j][r] + bcol[j];
                size_t cidx = (size_t)grow * N + gcol;
                if (mode == 0) {
                    ((float*)Cout)[cidx] = v + extra[(grow & 511) * 128 + gcol];
                } else if (mode == 2) {
                    ((float*)Cout)[cidx] = v + extra[cidx];
                } else if (mode == 5) {
                    float vq = (gcol < 128) ? v * QSCALE : v;
                    ((__hip_bfloat16*)Cout)[cidx] = __float2bfloat16(vq);
                } else {
                    ((float*)Cout)[cidx] = v;
                }
            }
        }
    }
}

// ---------------------------------------------------------------------------
// 3b. Fused MoE FFN: yw = (gelu(gather(zbf) @ w1 + b1) @ w2 + b2) * awt.
//     hid never leaves registers — see theory: hid^T C-layout = k-frag set,
//     second MFMA uses permuted w2t A-frags (bijection over 32 f's).
// ---------------------------------------------------------------------------
__global__ __launch_bounds__(256) void moe_kernel(
    const __hip_bfloat16* __restrict__ zbf,
    const __hip_bfloat16* __restrict__ w1t,   // [E][512 f][128 d]
    const float* __restrict__ b1,             // [E][512]
    const __hip_bfloat16* __restrict__ w2t,   // [E][128 d][512 f]
    const float* __restrict__ b2,             // [E][128]
    const int* __restrict__ moff, const int* __restrict__ atok,
    const float* __restrict__ awt, float* __restrict__ yw)
{
    __shared__ short tok[128 * 136];          // token tile (16B-aligned rows)
    __shared__ float patch[4][16 * 18];       // per-wave transpose patch
    const int tid = threadIdx.x;
    const int slot0 = blockIdx.x * 128;
    if (slot0 >= moff[8]) return;             // segments are 128-aligned
    int e = 0;
    while (moff[e + 1] <= slot0) ++e;
    const int lim = moff[e] + moff[9 + e];
    const __hip_bfloat16* w1e = w1t + (size_t)e * 512 * 128;
    const __hip_bfloat16* w2e = w2t + (size_t)e * 128 * 512;
    const float* b1e = b1 + e * 512;
    const float* b2e = b2 + e * 128;

    {   // stage gathered token rows: thread t -> row t>>1, half t&1
        int row = tid >> 1, half = tid & 1;
        int slot = slot0 + row;
        int src = (slot < lim) ? atok[slot] : BT;    // pad -> zeroed row
        const uint4* s = (const uint4*)(zbf + (size_t)src * 128 + half * 64);
        uint4* d = (uint4*)&tok[row * 136 + half * 64];
#pragma unroll
        for (int c = 0; c < 8; ++c) d[c] = s[c];
    }
    __syncthreads();

    const int wave = tid >> 6, lane = tid & 63;
    const int wm = (wave >> 1) * 64, wn = (wave & 1) * 64;   // d-half, token-half
    const int lr = lane & 15, q = lane >> 4;

    f32x4 acc[4][4];                          // yw^T [d][token]
#pragma unroll
    for (int i = 0; i < 4; ++i)
#pragma unroll
        for (int j = 0; j < 4; ++j) acc[i][j] = (f32x4){0.f, 0.f, 0.f, 0.f};

    for (int fc = 0; fc < 16; ++fc) {
        // w2t A-frags at permuted f-offsets: j<4 -> fc*32+q*4+j ; j>=4 -> +16
        short8 a2[4];
#pragma unroll
        for (int mt = 0; mt < 4; ++mt) {
            const __hip_bfloat16* p = w2e + (size_t)(wm + mt * 16 + lr) * 512 + fc * 32;
            short4v lo = *(const short4v*)(p + q * 4);
            short4v hi = *(const short4v*)(p + 16 + q * 4);
#pragma unroll
            for (int j = 0; j < 4; ++j) { a2[mt][j] = lo[j]; a2[mt][4 + j] = hi[j]; }
        }
        // first MFMA: hid^T[f-chunk 32][token 64], K = d = 128
        f32x4 hc[2][4];
#pragma unroll
        for (int mt = 0; mt < 2; ++mt)
#pragma unroll
            for (int nt = 0; nt < 4; ++nt) hc[mt][nt] = (f32x4){0.f, 0.f, 0.f, 0.f};
#pragma unroll
        for (int kk = 0; kk < 4; ++kk) {
            short8 a1[2];
#pragma unroll
            for (int mt = 0; mt < 2; ++mt)
                a1[mt] = *(const short8*)(w1e + (size_t)(fc * 32 + mt * 16 + lr) * 128
                                          + kk * 32 + q * 8);
            short8 bfr[4];
#pragma unroll
            for (int nt = 0; nt < 4; ++nt)
                bfr[nt] = *(const short8*)&tok[(wn + nt * 16 + lr) * 136 + kk * 32 + q * 8];
#pragma unroll
            for (int mt = 0; mt < 2; ++mt)
#pragma unroll
                for (int nt = 0; nt < 4; ++nt)
                    hc[mt][nt] = __builtin_amdgcn_mfma_f32_16x16x32_bf16(
                        a1[mt], bfr[nt], hc[mt][nt], 0, 0, 0);
        }
        // bias + gelu + truncate-pack; lane holds f = fc*32+q*4+j (mt0) / +16 (mt1)
        float bv0[4], bv1[4];
#pragma unroll
        for (int j = 0; j < 4; ++j) {
            bv0[j] = b1e[fc * 32 + q * 4 + j];
            bv1[j] = b1e[fc * 32 + 16 + q * 4 + j];
        }
#pragma unroll
        for (int nt = 0; nt < 4; ++nt) {
            short8 pf;
#pragma unroll
            for (int j = 0; j < 4; ++j) {
                float v0 = gelu_f(hc[0][nt][j] + bv0[j]);
                float v1 = gelu_f(hc[1][nt][j] + bv1[j]);
                pf[j]     = (short)(__float_as_uint(v0) >> 16);
                pf[4 + j] = (short)(__float_as_uint(v1) >> 16);
            }
#pragma unroll
            for (int mt = 0; mt < 4; ++mt)
                acc[mt][nt] = __builtin_amdgcn_mfma_f32_16x16x32_bf16(
                    a2[mt], pf, acc[mt][nt], 0, 0, 0);
        }
    }

    // epilogue: per-wave transpose via LDS patch -> coalesced f32 stores
    float* pp = patch[wave];
    const int sw = lane >> 2, dq = lane & 3;
#pragma unroll
    for (int mt = 0; mt < 4; ++mt) {
        float b2v[4];
#pragma unroll
        for (int r = 0; r < 4; ++r) b2v[r] = b2e[wm + mt * 16 + q * 4 + r];
#pragma unroll
        for (int nt = 0; nt < 4; ++nt) {
            float awv = awt[slot0 + wn + nt * 16 + lr];
#pragma unroll
            for (int r = 0; r < 4; ++r)
                pp[(q * 4 + r) * 18 + lr] = (acc[mt][nt][r] + b2v[r]) * awv;
            float4 o;
            o.x = pp[(dq * 4 + 0) * 18 + sw];
            o.y = pp[(dq * 4 + 1) * 18 + sw];
            o.z = pp[(dq * 4 + 2) * 18 + sw];
            o.w = pp[(dq * 4 + 3) * 18 + sw];
            *(float4*)&yw[(size_t)(slot0 + wn + nt * 16 + sw) * 128
                          + wm + mt * 16 + dq * 4] = o;
        }
    }
}

// ---------------------------------------------------------------------------
// 4. LayerNorm over D=128 -> bf16 zbf (layer-0 ln1 only)
// ---------------------------------------------------------------------------
__global__ __launch_bounds__(256) void ln_kernel(const float* __restrict__ x,
                                                 const float* __restrict__ g,
                                                 const float* __restrict__ b,
                                                 __hip_bfloat16* __restrict__ zbf) {
    int wave = threadIdx.x >> 6, lane = threadIdx.x & 63;
    size_t row = (size_t)blockIdx.x * 4 + wave;
    const float* xr = x + row * 128;
    float a0 = xr[lane], a1 = xr[lane + 64];
    float s = a0 + a1;
#pragma unroll
    for (int off = 32; off > 0; off >>= 1) s += __shfl_xor(s, off);
    float mean = s * (1.f / 128.f);
    float d0 = a0 - mean, d1 = a1 - mean;
    float v = d0 * d0 + d1 * d1;
#pragma unroll
    for (int off = 32; off > 0; off >>= 1) v += __shfl_xor(v, off);
    float inv = rsqrtf(v * (1.f / 128.f) + 1e-5f);
    zbf[row * 128 + lane]      = __float2bfloat16(d0 * inv * g[lane] + b[lane]);
    zbf[row * 128 + lane + 64] = __float2bfloat16(d1 * inv * g[lane + 64] + b[lane + 64]);
}

// ---------------------------------------------------------------------------
// 5. MFMA flash attention v3 — shuffle-free PV + 512 threads (8 waves).
// ---------------------------------------------------------------------------
__global__ __launch_bounds__(512) void attn_kernel(const __hip_bfloat16* __restrict__ qkv,
                                                   __hip_bfloat16* __restrict__ o) {
    __shared__ short Ks[512 * 24];    // K [key][16 used, 24 pitch]
    __shared__ short Vt[17 * 520];    // V^T [col 0..15, 16=ones][key]
    const int b = blockIdx.z, hh = blockIdx.y, half = blockIdx.x;
    const int tid = threadIdx.x;
    const size_t base = (size_t)b * 512 * 384;

    {
        int r = tid;
        const uint4* ksrc = (const uint4*)(qkv + base + (size_t)r * 384 + 128 + hh * 16);
        uint4 k0 = ksrc[0], k1 = ksrc[1];
        *(uint4*)&Ks[r * 24 + 0] = k0;
        *(uint4*)&Ks[r * 24 + 8] = k1;
        const uint4* vsrc = (const uint4*)(qkv + base + (size_t)r * 384 + 256 + hh * 16);
        uint4 v0 = vsrc[0], v1 = vsrc[1];
        unsigned vv[8] = {v0.x, v0.y, v0.z, v0.w, v1.x, v1.y, v1.z, v1.w};
#pragma unroll
        for (int c = 0; c < 8; ++c) {
            Vt[(2 * c)     * 520 + r] = (short)(vv[c] & 0xffff);
            Vt[(2 * c + 1) * 520 + r] = (short)(vv[c] >> 16);
        }
        Vt[16 * 520 + r] = (short)0x3F80;
    }
    __syncthreads();

    const int wave = tid >> 6, lane = tid & 63;
    const int lm = lane & 31, lh = lane >> 5;
    const int qrow0 = half * 256 + wave * 32;

    short8 qf = *(const short8*)(qkv + base + (size_t)(qrow0 + lm) * 384 + hh * 16 + lh * 8);

    f32x16 accO;
#pragma unroll
    for (int r = 0; r < 16; ++r) accO[r] = 0.f;

    for (int kc = 0; kc < 16; ++kc) {
        short8 kf = *(const short8*)&Ks[(kc * 32 + lm) * 24 + lh * 8];
        int vr = (lm < 16) ? lm : 16;
        const short* vb2 = &Vt[vr * 520 + kc * 32];
        short4v va  = *(const short4v*)(vb2 + 4 * lh);
        short4v vbq = *(const short4v*)(vb2 + 8 + 4 * lh);
        short4v vc  = *(const short4v*)(vb2 + 16 + 4 * lh);
        short4v vd  = *(const short4v*)(vb2 + 24 + 4 * lh);
        short8 vf0, vf1;
#pragma unroll
        for (int j = 0; j < 4; ++j) {
            vf0[j] = va[j];  vf0[4 + j] = vbq[j];
            vf1[j] = vc[j];  vf1[4 + j] = vd[j];
        }
        f32x16 st;
#pragma unroll
        for (int r = 0; r < 16; ++r) st[r] = 0.f;
        st = __builtin_amdgcn_mfma_f32_32x32x16_bf16(kf, qf, st, 0, 0, 0);
        short8 pf0, pf1;
#pragma unroll
        for (int r = 0; r < 8; ++r) {
            pf0[r] = (short)(__float_as_uint(exp2f(st[r]))     >> 16);
            pf1[r] = (short)(__float_as_uint(exp2f(st[8 + r])) >> 16);
        }
        accO = __builtin_amdgcn_mfma_f32_32x32x16_bf16(pf0, vf0, accO, 0, 0, 0);
        accO = __builtin_amdgcn_mfma_f32_32x32x16_bf16(pf1, vf1, accO, 0, 0, 0);
    }

#pragma unroll
    for (int r = 0; r < 16; ++r) {
        float val = accO[r];
        float s = __shfl(val, (lane & 32) + 16);
        if (lm < 16) {
            int qr = qrow0 + (r & 3) + 8 * (r >> 2) + 4 * lh;
            o[((size_t)b * 512 + qr) * 128 + hh * 16 + lm] = __float2bfloat16(val / s);
        }
    }
}

// ---------------------------------------------------------------------------
// 6. Fused LN2 + router (64-slot atomic spread)
// ---------------------------------------------------------------------------
__global__ __launch_bounds__(256) void ln2gate_kernel(
    const float* __restrict__ x, const float* __restrict__ g, const float* __restrict__ b,
    const float* __restrict__ gW, __hip_bfloat16* __restrict__ zbf,
    int* __restrict__ topi, float* __restrict__ topw,
    float* __restrict__ impS, int* __restrict__ cntS)
{
    __shared__ float simp[8];
    __shared__ int scnt[8];
    const int tid = threadIdx.x;
    if (tid < 8) { simp[tid] = 0.f; scnt[tid] = 0; }
    __syncthreads();
    const int wave = tid >> 6, lane = tid & 63;
    const size_t row = (size_t)blockIdx.x * 4 + wave;
    const float* xr = x + row * 128;
    float a0 = xr[lane], a1 = xr[lane + 64];
    float s = a0 + a1;
#pragma unroll
    for (int off = 32; off > 0; off >>= 1) s += __shfl_xor(s, off);
    float mean = s * (1.f / 128.f);
    float d0 = a0 - mean, d1 = a1 - mean;
    float v = d0 * d0 + d1 * d1;
#pragma unroll
    for (int off = 32; off > 0; off >>= 1) v += __shfl_xor(v, off);
    float inv = rsqrtf(v * (1.f / 128.f) + 1e-5f);
    float o0 = d0 * inv * g[lane] + b[lane];
    float o1 = d1 * inv * g[lane + 64] + b[lane + 64];
    zbf[row * 128 + lane]      = __float2bfloat16(o0);
    zbf[row * 128 + lane + 64] = __float2bfloat16(o1);
    float4 gA = *(const float4*)&gW[lane * 8];
    float4 gB = *(const float4*)&gW[lane * 8 + 4];
    float4 gC = *(const float4*)&gW[(lane + 64) * 8];
    float4 gD = *(const float4*)&gW[(lane + 64) * 8 + 4];
    float lg[8];
    lg[0] = o0 * gA.x + o1 * gC.x;  lg[1] = o0 * gA.y + o1 * gC.y;
    lg[2] = o0 * gA.z + o1 * gC.z;  lg[3] = o0 * gA.w + o1 * gC.w;
    lg[4] = o0 * gB.x + o1 * gD.x;  lg[5] = o0 * gB.y + o1 * gD.y;
    lg[6] = o0 * gB.z + o1 * gD.z;  lg[7] = o0 * gB.w + o1 * gD.w;
#pragma unroll
    for (int e = 0; e < 8; ++e)
#pragma unroll
        for (int off = 32; off > 0; off >>= 1) lg[e] += __shfl_xor(lg[e], off);
    if (lane == 0) {
        float p[8];
        float mx = lg[0];
#pragma unroll
        for (int k = 1; k < 8; ++k) mx = fmaxf(mx, lg[k]);
        float ssum = 0.f;
#pragma unroll
        for (int k = 0; k < 8; ++k) { p[k] = expf(lg[k] - mx); ssum += p[k]; }
        float pinv = 1.f / ssum;
#pragma unroll
        for (int k = 0; k < 8; ++k) p[k] *= pinv;
        int i0 = 0; float v0 = p[0];
#pragma unroll
        for (int k = 1; k < 8; ++k) if (p[k] > v0) { v0 = p[k]; i0 = k; }
        int i1 = -1; float v1 = -1.f;
#pragma unroll
        for (int k = 0; k < 8; ++k) if (k != i0 && p[k] > v1) { v1 = p[k]; i1 = k; }
        float wsum = v0 + v1;
        topi[row * 2] = i0;  topi[row * 2 + 1] = i1;
        topw[row * 2] = v0 / wsum;  topw[row * 2 + 1] = v1 / wsum;
#pragma unroll
        for (int k = 0; k < 8; ++k) atomicAdd(&simp[k], p[k]);
        atomicAdd(&scnt[i0], 1); atomicAdd(&scnt[i1], 1);
    }
    __syncthreads();
    if (tid < 8) {
        int slot = (blockIdx.x & 63) * 8 + tid;
        atomicAdd(&impS[slot], simp[tid]);
        atomicAdd(&cntS[slot], scnt[tid]);
    }
}

// ---------------------------------------------------------------------------
// 7. Sum spread counts, 128-aligned scan, counts, fill init, aux
// ---------------------------------------------------------------------------
__global__ void offsets_kernel(const int* __restrict__ cntS, const float* __restrict__ impS,
                               int* __restrict__ moff, int* __restrict__ fill,
                               float* __restrict__ aux) {
    int c[8]; float im[8];
    for (int e = 0; e < 8; ++e) { c[e] = 0; im[e] = 0.f; }
    for (int sl = 0; sl < 64; ++sl)
        for (int e = 0; e < 8; ++e) { c[e] += cntS[sl * 8 + e]; im[e] += impS[sl * 8 + e]; }
    int t = 0;
    float s = 0.f;
    for (int e = 0; e < 8; ++e) {
        moff[e] = t; fill[e] = t;
        moff[9 + e] = c[e];
        t += (c[e] + 127) & ~127;
        s += (im[e] * (1.f / 16384.f)) * ((float)c[e] * (1.f / 16384.f));
    }
    moff[8] = t;
    aux[0] += 8.f * s;
}

// ---------------------------------------------------------------------------
// 8. Scatter tokens into expert-contiguous slots — LDS-aggregated atomics.
// ---------------------------------------------------------------------------
__global__ __launch_bounds__(256) void scatter_kernel(const int* __restrict__ topi,
                                                      const float* __restrict__ topw,
                                                      int* __restrict__ fill, int* __restrict__ atok,
                                                      float* __restrict__ awt, int* __restrict__ tokpos) {
    __shared__ int lcnt[8];
    __shared__ int lbase[8];
    const int tid = threadIdx.x;
    const int token = blockIdx.x * 256 + tid;
    if (tid < 8) lcnt[tid] = 0;
    __syncthreads();
    const int e0 = topi[token * 2], e1 = topi[token * 2 + 1];
    const float w0 = topw[token * 2], w1 = topw[token * 2 + 1];
    const int l0 = atomicAdd(&lcnt[e0], 1);
    const int l1 = atomicAdd(&lcnt[e1], 1);
    __syncthreads();
    if (tid < 8) lbase[tid] = atomicAdd(&fill[tid], lcnt[tid]);
    __syncthreads();
    const int p0 = lbase[e0] + l0;
    const int p1 = lbase[e1] + l1;
    atok[p0] = token;  awt[p0] = w0;  tokpos[token * 2]     = p0;
    atok[p1] = token;  awt[p1] = w1;  tokpos[token * 2 + 1] = p1;
}

// ---------------------------------------------------------------------------
// 9. Fused combine + next-layer LN1
// ---------------------------------------------------------------------------
__global__ __launch_bounds__(256) void combine_ln_kernel(
    const float* __restrict__ yw, const int* __restrict__ tokpos,
    float* __restrict__ h, const float* __restrict__ g, const float* __restrict__ b,
    __hip_bfloat16* __restrict__ zbf)
{
    const int tid = threadIdx.x;
    const int wave = tid >> 6, lane = tid & 63;
    const size_t row = (size_t)blockIdx.x * 4 + wave;
    const int p0 = tokpos[row * 2], p1 = tokpos[row * 2 + 1];
    float a0 = h[row * 128 + lane]      + yw[(size_t)p0 * 128 + lane]
             + yw[(size_t)p1 * 128 + lane];
    float a1 = h[row * 128 + lane + 64] + yw[(size_t)p0 * 128 + lane + 64]
             + yw[(size_t)p1 * 128 + lane + 64];
    h[row * 128 + lane]      = a0;
    h[row * 128 + lane + 64] = a1;
    if (zbf) {
        float s = a0 + a1;
#pragma unroll
        for (int off = 32; off > 0; off >>= 1) s += __shfl_xor(s, off);
        float mean = s * (1.f / 128.f);
        float d0 = a0 - mean, d1 = a1 - mean;
        float v = d0 * d0 + d1 * d1;
#pragma unroll
        for (int off = 32; off > 0; off >>= 1) v += __shfl_xor(v, off);
        float inv = rsqrtf(v * (1.f / 128.f) + 1e-5f);
        zbf[row * 128 + lane]      = __float2bfloat16(d0 * inv * g[lane] + b[lane]);
        zbf[row * 128 + lane + 64] = __float2bfloat16(d1 * inv * g[lane + 64] + b[lane + 64]);
    }
}

// ---------------------------------------------------------------------------
// 10. mean over T -> LN -> head matmul [128,2]; writes aux scalar
// ---------------------------------------------------------------------------
__global__ __launch_bounds__(128) void head_kernel(const float* __restrict__ h,
                                                   const float* __restrict__ g,
                                                   const float* __restrict__ bb,
                                                   const float* __restrict__ hW,
                                                   const float* __restrict__ hb,
                                                   const float* __restrict__ aux,
                                                   float* __restrict__ out) {
    __shared__ float red[128];
    __shared__ float pl[128];
    int b = blockIdx.x, tid = threadIdx.x;
    float s = 0.f;
    for (int t = 0; t < 512; ++t) s += h[((size_t)b * 512 + t) * 128 + tid];
    float pooled = s * (1.f / 512.f);
    red[tid] = pooled; __syncthreads();
    for (int st = 64; st > 0; st >>= 1) { if (tid < st) red[tid] += red[tid + st]; __syncthreads(); }
    float mean = red[0] * (1.f / 128.f);
    __syncthreads();
    float d = pooled - mean;
    red[tid] = d * d; __syncthreads();
    for (int st = 64; st > 0; st >>= 1) { if (tid < st) red[tid] += red[tid + st]; __syncthreads(); }
    float var = red[0] * (1.f / 128.f);
    float ln = d / sqrtf(var + 1e-5f) * g[tid] + bb[tid];
    pl[tid] = ln; __syncthreads();
    if (tid < 2) {
        float acc = hb[tid];
        for (int k = 0; k < 128; ++k) acc += pl[k] * hW[k * 2 + tid];
        out[b * 2 + tid] = acc;
    }
    if (b == 0 && tid == 0) out[64] = aux[0];
}

// ---------------------------------------------------------------------------
extern "C" void kernel_launch(void* const* d_in, const int* in_sizes, int n_in,
                              void* d_out, int out_size, void* d_ws, size_t ws_size,
                              hipStream_t stream) {
    (void)in_sizes; (void)n_in; (void)out_size; (void)ws_size;
    const float* x      = (const float*)d_in[0];
    const float* proj_W = (const float*)d_in[1];
    const float* proj_b = (const float*)d_in[2];
    const float* pos    = (const float*)d_in[3];
    const float* ln1_g  = (const float*)d_in[4];
    const float* ln1_b  = (const float*)d_in[5];
    const float* qkv_W  = (const float*)d_in[6];
    const float* qkv_b  = (const float*)d_in[7];
    const float* out_W  = (const float*)d_in[8];
    const float* out_b  = (const float*)d_in[9];
    const float* ln2_g  = (const float*)d_in[10];
    const float* ln2_b  = (const float*)d_in[11];
    const float* gate_W = (const float*)d_in[12];
    const float* w1     = (const float*)d_in[13];
    const float* b1     = (const float*)d_in[14];
    const float* w2     = (const float*)d_in[15];
    const float* b2     = (const float*)d_in[16];
    const float* hl_g   = (const float*)d_in[17];
    const float* hl_b   = (const float*)d_in[18];
    const float* head_W = (const float*)d_in[19];
    const float* head_b = (const float*)d_in[20];
    float* outp = (float*)d_out;

    float* ws = (float*)d_ws;
    size_t off = 0;
    auto alloc = [&](size_t n) { float* p = ws + off; off += (n + 63) & ~(size_t)63; return p; };
    float* xtb_f   = alloc((size_t)BT * 224);         // bf16 [16384][448]
    float* h       = alloc((size_t)BT * 128);
    float* zbf_f   = alloc((size_t)(BT + 1) * 64);    // bf16 [16385][128], row BT = zeros
    float* qkvbf_f = alloc((size_t)BT * 192);         // bf16 [16384][384]
    float* obbf_f  = alloc((size_t)BT * 64);          // bf16 [16384][128]
    float* yw      = alloc((size_t)MAXASSIGN * 128);  // f32
    float* projWt_f= alloc(128 * 448 / 2);
    float* qkvWt_f = alloc(4 * 384 * 128 / 2);
    float* outWt_f = alloc(4 * 128 * 128 / 2);
    float* w1t_f   = alloc((size_t)32 * 512 * 128 / 2);
    float* w2t_f   = alloc((size_t)32 * 128 * 512 / 2);
    float* topw    = alloc(32768);
    float* awt     = alloc(MAXASSIGN);
    float* impc    = alloc(1024);
    float* auxp    = alloc(1);
    int* topi      = (int*)alloc(32768);
    int* atok      = (int*)alloc(MAXASSIGN);
    int* tokpos    = (int*)alloc(32768);
    int* moff      = (int*)alloc(32);
    int* fill      = (int*)alloc(8);
    float* impS    = impc;
    int*   cntS    = (int*)(impc + 512);

    __hip_bfloat16* xtb    = (__hip_bfloat16*)xtb_f;
    __hip_bfloat16* zbf    = (__hip_bfloat16*)zbf_f;
    __hip_bfloat16* qkvbf  = (__hip_bfloat16*)qkvbf_f;
    __hip_bfloat16* obbf   = (__hip_bfloat16*)obbf_f;
    __hip_bfloat16* projWt = (__hip_bfloat16*)projWt_f;
    __hip_bfloat16* qkvWt  = (__hip_bfloat16*)qkvWt_f;
    __hip_bfloat16* outWt  = (__hip_bfloat16*)outWt_f;
    __hip_bfloat16* w1t    = (__hip_bfloat16*)w1t_f;
    __hip_bfloat16* w2t    = (__hip_bfloat16*)w2t_f;

    hipMemsetAsync(auxp, 0, 4, stream);
    hipMemsetAsync((char*)zbf + (size_t)BT * 256, 0, 256, stream);   // zero gather row

    transpose_kernel<<<28672, 256, 0, stream>>>(x, xtb);
    projconv_kernel<<<224, 256, 0, stream>>>(proj_W, projWt);
    wconv_kernel<<<768, 256, 0, stream>>>(qkv_W, qkvWt, 128, 384, 4 * 128 * 384);
    wconv_kernel<<<256, 256, 0, stream>>>(out_W, outWt, 128, 128, 4 * 128 * 128);
    wconv_kernel<<<8192, 256, 0, stream>>>(w1, w1t, 128, 512, 32 * 128 * 512);
    wconv_kernel<<<8192, 256, 0, stream>>>(w2, w2t, 512, 128, 32 * 512 * 128);

    mm_kernel<<<dim3(128, 1), 256, 0, stream>>>(xtb, projWt, proj_b, pos, h, 448, 128, 0);
    ln_kernel<<<4096, 256, 0, stream>>>(h, ln1_g, ln1_b, zbf);

    for (int i = 0; i < 4; ++i) {
        mm_kernel<<<dim3(128, 3), 256, 0, stream>>>(zbf, qkvWt + (size_t)i * 384 * 128,
                                                    qkv_b + i * 384, nullptr, qkvbf,
                                                    128, 384, 5);
        attn_kernel<<<dim3(2, 8, 32), 512, 0, stream>>>(qkvbf, obbf);
        mm_kernel<<<dim3(128, 1), 256, 0, stream>>>(obbf, outWt + (size_t)i * 128 * 128,
                                                    out_b + i * 128, h, h, 128, 128, 2);
        hipMemsetAsync(impc, 0, 4096, stream);
        ln2gate_kernel<<<4096, 256, 0, stream>>>(h, ln2_g + i * 128, ln2_b + i * 128,
                                                 gate_W + (size_t)i * 128 * 8, zbf,
                                                 topi, topw, impS, cntS);
        offsets_kernel<<<1, 1, 0, stream>>>(cntS, impS, moff, fill, auxp);
        scatter_kernel<<<64, 256, 0, stream>>>(topi, topw, fill, atok, awt, tokpos);
        // fused MoE FFN (replaces moe1+moe2; hid stays in registers)
        moe_kernel<<<264, 256, 0, stream>>>(zbf,
                                            w1t + (size_t)i * 8 * 512 * 128,
                                            b1 + (size_t)i * 8 * 512,
                                            w2t + (size_t)i * 8 * 128 * 512,
                                            b2 + (size_t)i * 8 * 128,
                                            moff, atok, awt, yw);
        combine_ln_kernel<<<4096, 256, 0, stream>>>(yw, tokpos, h,
                                                    ln1_g + (i + 1 < 4 ? (i + 1) * 128 : 0),
                                                    ln1_b + (i + 1 < 4 ? (i + 1) * 128 : 0),
                                                    (i < 3) ? zbf : (__hip_bfloat16*)nullptr);
    }
    head_kernel<<<32, 128, 0, stream>>>(h, hl_g, hl_b, head_W, head_b, auxp, outp);
}

// Round 13
// 903.748 us; speedup vs baseline: 1.0780x; 1.0780x over previous
//
#include <hip/hip_runtime.h>
#include <hip/hip_bf16.h>
#include <cstdint>
#include <cstddef>

// ---------------------------------------------------------------------------
// Model constants
// ---------------------------------------------------------------------------
#define BT        16384          // B*T tokens
#define MAXASSIGN 33792          // 32768 + 8*127 rounded to 128-aligned segments
#define QSCALE    0.36067376022224085f   // 0.25 * log2(e): fold 1/sqrt(dh) + exp->exp2

typedef __attribute__((ext_vector_type(8)))  short short8;   // 8 bf16 = 1 MFMA frag
typedef __attribute__((ext_vector_type(4)))  short short4v;
typedef __attribute__((ext_vector_type(4)))  float f32x4;
typedef __attribute__((ext_vector_type(16))) float f32x16;

// gelu(x) = 0.5x(1+tanh(u)) = x*sigmoid(2u), u = sqrt(2/pi)(x+0.044715x^3).
// e = exp2(2u*log2e); result = x*e/(e+1). 1 exp + 1 rcp vs libm tanhf's ~28 ops.
__device__ __forceinline__ float gelu_f(float x) {
    float u2l = (x + 0.044715f * x * x * x) * 2.3022081927f;   // 2u*log2(e)
    float e = exp2f(u2l);
    float r = __builtin_amdgcn_rcpf(e + 1.0f);
    return x * e * r;
}

// ---------------------------------------------------------------------------
// 1. x [32,55,512,8] -> xtb [16384][448] bf16 (cols 440..447 zero-padded)
// ---------------------------------------------------------------------------
__global__ __launch_bounds__(256) void transpose_kernel(const float* __restrict__ x,
                                                        __hip_bfloat16* __restrict__ xtb) {
    int idx = blockIdx.x * 256 + threadIdx.x;      // 16384*448 threads exact
    int j   = idx % 448;
    int row = idx / 448;
    int t   = row & 511;
    int b   = row >> 9;
    float v = 0.f;
    if (j < 440) {
        int nb = j >> 3, nc = j & 7;
        v = x[(((size_t)(b * 55 + nb)) * 512 + t) * 8 + nc];
    }
    xtb[idx] = __float2bfloat16(v);
}

// ---------------------------------------------------------------------------
// 2. Weight convert+transpose: out[b][n][k] = bf16(in[b][k][n])
// ---------------------------------------------------------------------------
__global__ __launch_bounds__(256) void wconv_kernel(const float* __restrict__ in,
                                                    __hip_bfloat16* __restrict__ out,
                                                    int K, int N, int total) {
    int idx = blockIdx.x * 256 + threadIdx.x;
    if (idx >= total) return;
    int k = idx % K; int rem = idx / K; int n = rem % N; int b = rem / N;
    out[idx] = __float2bfloat16(in[((size_t)b * K + k) * N + n]);
}

// proj_W [440][128] -> projWt [128][448] bf16 with zero pad k>=440
__global__ __launch_bounds__(256) void projconv_kernel(const float* __restrict__ in,
                                                       __hip_bfloat16* __restrict__ out) {
    int idx = blockIdx.x * 256 + threadIdx.x;      // 128*448 exact
    int k = idx % 448, n = idx / 448;
    out[idx] = __float2bfloat16(k < 440 ? in[k * 128 + n] : 0.f);
}

// ---------------------------------------------------------------------------
// 3. bf16 MFMA GEMM: C[M,N] = A[M,K](bf16) @ Wt[N,K](bf16)^T (+ epilogue)
//    128x128 tile, BK=64, 256 threads (4 waves, 2x2), 4x4 frags of
//    mfma_f32_16x16x32_bf16. LDS chunk-XOR swizzle -> conflict-free both ways.
//    R9 staging (no register prefetch: R10 spilled, +78 MB/dispatch).
//    MoE stays as two mm_kernel passes: the R12 fused moe_kernel halved
//    traffic but dropped to 264 blocks = 1 block/CU (occupancy 5.7%) and
//    2x-redundant hid -> 93 us/layer. Grid parallelism > traffic here.
//    mode 3: gathered A via atok, bounds-check vs moff[e]+moff[9+e]
//    mode 5: bf16 out, Q-part (gcol<128) pre-scaled by QSCALE
// ---------------------------------------------------------------------------
__global__ __launch_bounds__(256) void mm_kernel(
    const __hip_bfloat16* __restrict__ A, const __hip_bfloat16* __restrict__ Wt,
    const float* __restrict__ bias, const float* __restrict__ extra,
    void* __restrict__ Cout, int K, int N, int mode, int wstride,
    const int* __restrict__ moff, const int* __restrict__ atok,
    const float* __restrict__ awt)
{
    __shared__ short As[128 * 64];   // 16 KB, chunk-swizzled [row][c^(row&7)]
    __shared__ short Bs[128 * 64];   // 16 KB
    const int tid  = threadIdx.x;
    const int row0 = blockIdx.x * 128;
    const int col0 = blockIdx.y * 128;

    const float* bias2 = bias;
    int lim = 0;
    if (mode >= 3 && mode <= 4) {
        if (row0 >= moff[8]) return;             // segments are 128-aligned
        int e = 0;
        while (moff[e + 1] <= row0) ++e;
        Wt    += (size_t)e * wstride;
        bias2  = bias + e * N;
        lim    = moff[e] + moff[9 + e];          // valid-assignment end
    }

    const int crow = tid >> 3;   // 0..31  (staging row within p-group)
    const int cc   = tid & 7;    // 0..7   (16B chunk within row)

    f32x4 acc[4][4];
#pragma unroll
    for (int i = 0; i < 4; ++i)
#pragma unroll
        for (int j = 0; j < 4; ++j) acc[i][j] = (f32x4){0.f, 0.f, 0.f, 0.f};

    const int wave = tid >> 6, lane = tid & 63;
    const int wm = (wave >> 1) * 64, wn = (wave & 1) * 64;
    const int lr = lane & 15, q = lane >> 4;

    for (int k0 = 0; k0 < K; k0 += 64) {
#pragma unroll
        for (int p = 0; p < 4; ++p) {
            int row = p * 32 + crow;
            int src_row = row0 + row;
            if (mode == 3) {
                int grow = row0 + row;
                src_row = (grow < lim) ? atok[grow] : BT;   // pad -> zeroed row
            }
            uint4 va = *(const uint4*)(A + (size_t)src_row * K + k0 + cc * 8);
            *(uint4*)&As[(row * 8 + (cc ^ (row & 7))) * 8] = va;
            uint4 vb = *(const uint4*)(Wt + (size_t)(col0 + row) * K + k0 + cc * 8);
            *(uint4*)&Bs[(row * 8 + (cc ^ (row & 7))) * 8] = vb;
        }
        __syncthreads();
#pragma unroll
        for (int s = 0; s < 2; ++s) {
            short8 af[4], bf[4];
#pragma unroll
            for (int f = 0; f < 4; ++f) {
                int m = wm + f * 16 + lr;
                af[f] = *(const short8*)&As[(m * 8 + ((s * 4 + q) ^ (m & 7))) * 8];
                int n = wn + f * 16 + lr;
                bf[f] = *(const short8*)&Bs[(n * 8 + ((s * 4 + q) ^ (n & 7))) * 8];
            }
#pragma unroll
            for (int i = 0; i < 4; ++i)
#pragma unroll
                for (int j = 0; j < 4; ++j)
                    acc[i][j] = __builtin_amdgcn_mfma_f32_16x16x32_bf16(
                        af[i], bf[j], acc[i][j], 0, 0, 0);
        }
        __syncthreads();
    }

    // epilogue: C/D mapping col = lane&15 (n), row = q*4 + reg (m)
    float bcol[4];
#pragma unroll
    for (int j = 0; j < 4; ++j) bcol[j] = bias2[col0 + wn + j * 16 + lr];
#pragma unroll
    for (int i = 0; i < 4; ++i) {
#pragma unroll
        for (int r = 0; r < 4; ++r) {
            int grow = row0 + wm + i * 16 + q * 4 + r;
            float aw = (mode == 4) ? awt[grow] : 0.f;
#pragma unroll
            for (int j = 0; j < 4; ++j) {
                int gcol = col0 + wn + j * 16 + lr;
                float v = acc[i][j][r] + bcol[j];
                size_t cidx = (size_t)grow * N + gcol;
                if (mode == 0) {
                    ((float*)Cout)[cidx] = v + extra[(grow & 511) * 128 + gcol];
                } else if (mode == 2) {
                    ((float*)Cout)[cidx] = v + extra[cidx];
                } else if (mode == 3) {
                    ((__hip_bfloat16*)Cout)[cidx] = __float2bfloat16(gelu_f(v));
                } else if (mode == 4) {
                    ((float*)Cout)[cidx] = v * aw;
                } else if (mode == 5) {
                    float vq = (gcol < 128) ? v * QSCALE : v;
                    ((__hip_bfloat16*)Cout)[cidx] = __float2bfloat16(vq);
                } else {
                    ((float*)Cout)[cidx] = v;
                }
            }
        }
    }
}

// ---------------------------------------------------------------------------
// 4. LayerNorm over D=128 -> bf16 zbf (layer-0 ln1 only)
// ---------------------------------------------------------------------------
__global__ __launch_bounds__(256) void ln_kernel(const float* __restrict__ x,
                                                 const float* __restrict__ g,
                                                 const float* __restrict__ b,
                                                 __hip_bfloat16* __restrict__ zbf) {
    int wave = threadIdx.x >> 6, lane = threadIdx.x & 63;
    size_t row = (size_t)blockIdx.x * 4 + wave;
    const float* xr = x + row * 128;
    float a0 = xr[lane], a1 = xr[lane + 64];
    float s = a0 + a1;
#pragma unroll
    for (int off = 32; off > 0; off >>= 1) s += __shfl_xor(s, off);
    float mean = s * (1.f / 128.f);
    float d0 = a0 - mean, d1 = a1 - mean;
    float v = d0 * d0 + d1 * d1;
#pragma unroll
    for (int off = 32; off > 0; off >>= 1) v += __shfl_xor(v, off);
    float inv = rsqrtf(v * (1.f / 128.f) + 1e-5f);
    zbf[row * 128 + lane]      = __float2bfloat16(d0 * inv * g[lane] + b[lane]);
    zbf[row * 128 + lane + 64] = __float2bfloat16(d1 * inv * g[lane + 64] + b[lane + 64]);
}

// ---------------------------------------------------------------------------
// 5. MFMA flash attention v3 — shuffle-free PV + 512 threads (8 waves).
// ---------------------------------------------------------------------------
__global__ __launch_bounds__(512) void attn_kernel(const __hip_bfloat16* __restrict__ qkv,
                                                   __hip_bfloat16* __restrict__ o) {
    __shared__ short Ks[512 * 24];    // K [key][16 used, 24 pitch] : 24 KB
    __shared__ short Vt[17 * 520];    // V^T [col 0..15, 16=ones][key, 520 pitch]
    const int b = blockIdx.z, hh = blockIdx.y, half = blockIdx.x;
    const int tid = threadIdx.x;
    const size_t base = (size_t)b * 512 * 384;

    // ---- stage K rows and transposed V (+ ones row): one key row/thread ----
    {
        int r = tid;   // 512 threads, 512 keys
        const uint4* ksrc = (const uint4*)(qkv + base + (size_t)r * 384 + 128 + hh * 16);
        uint4 k0 = ksrc[0], k1 = ksrc[1];
        *(uint4*)&Ks[r * 24 + 0] = k0;
        *(uint4*)&Ks[r * 24 + 8] = k1;
        const uint4* vsrc = (const uint4*)(qkv + base + (size_t)r * 384 + 256 + hh * 16);
        uint4 v0 = vsrc[0], v1 = vsrc[1];
        unsigned vv[8] = {v0.x, v0.y, v0.z, v0.w, v1.x, v1.y, v1.z, v1.w};
#pragma unroll
        for (int c = 0; c < 8; ++c) {
            Vt[(2 * c)     * 520 + r] = (short)(vv[c] & 0xffff);
            Vt[(2 * c + 1) * 520 + r] = (short)(vv[c] >> 16);
        }
        Vt[16 * 520 + r] = (short)0x3F80;   // 1.0 bf16
    }
    __syncthreads();

    const int wave = tid >> 6, lane = tid & 63;
    const int lm = lane & 31, lh = lane >> 5;
    const int qrow0 = half * 256 + wave * 32;

    // Q B-frag (B[k=dh][n=qrow]): lane holds Q[qrow0+lm][8*lh + j]
    short8 qf = *(const short8*)(qkv + base + (size_t)(qrow0 + lm) * 384 + hh * 16 + lh * 8);

    f32x16 accO;
#pragma unroll
    for (int r = 0; r < 16; ++r) accO[r] = 0.f;

    for (int kc = 0; kc < 16; ++kc) {
        // K A-frag: A[m=key][k=dh]
        short8 kf = *(const short8*)&Ks[(kc * 32 + lm) * 24 + lh * 8];
        int vr = (lm < 16) ? lm : 16;    // cols >16 duplicate rowsum (unread)
        const short* vb2 = &Vt[vr * 520 + kc * 32];
        // permuted V B-frags: position j<4 -> key 4lh+j (+8/+16/+24 offsets)
        short4v va  = *(const short4v*)(vb2 + 4 * lh);
        short4v vbq = *(const short4v*)(vb2 + 8 + 4 * lh);
        short4v vc  = *(const short4v*)(vb2 + 16 + 4 * lh);
        short4v vd  = *(const short4v*)(vb2 + 24 + 4 * lh);
        short8 vf0, vf1;
#pragma unroll
        for (int j = 0; j < 4; ++j) {
            vf0[j] = va[j];  vf0[4 + j] = vbq[j];
            vf1[j] = vc[j];  vf1[4 + j] = vd[j];
        }
        f32x16 st;
#pragma unroll
        for (int r = 0; r < 16; ++r) st[r] = 0.f;
        st = __builtin_amdgcn_mfma_f32_32x32x16_bf16(kf, qf, st, 0, 0, 0);
        short8 pf0, pf1;
#pragma unroll
        for (int r = 0; r < 8; ++r) {
            pf0[r] = (short)(__float_as_uint(exp2f(st[r]))     >> 16);
            pf1[r] = (short)(__float_as_uint(exp2f(st[8 + r])) >> 16);
        }
        accO = __builtin_amdgcn_mfma_f32_32x32x16_bf16(pf0, vf0, accO, 0, 0, 0);
        accO = __builtin_amdgcn_mfma_f32_32x32x16_bf16(pf1, vf1, accO, 0, 0, 0);
    }

    // ---- epilogue: col n<16 = O_unnorm, col 16 = rowsum ----
#pragma unroll
    for (int r = 0; r < 16; ++r) {
        float val = accO[r];
        float s = __shfl(val, (lane & 32) + 16);   // n=16 lane, same half
        if (lm < 16) {
            int qr = qrow0 + (r & 3) + 8 * (r >> 2) + 4 * lh;
            o[((size_t)b * 512 + qr) * 128 + hh * 16 + lm] = __float2bfloat16(val / s);
        }
    }
}

// ---------------------------------------------------------------------------
// 6. Fused LN2 + router (R7-measured structure: atomics spread over 64 slots)
// ---------------------------------------------------------------------------
__global__ __launch_bounds__(256) void ln2gate_kernel(
    const float* __restrict__ x, const float* __restrict__ g, const float* __restrict__ b,
    const float* __restrict__ gW, __hip_bfloat16* __restrict__ zbf,
    int* __restrict__ topi, float* __restrict__ topw,
    float* __restrict__ impS, int* __restrict__ cntS)
{
    __shared__ float simp[8];
    __shared__ int scnt[8];
    const int tid = threadIdx.x;
    if (tid < 8) { simp[tid] = 0.f; scnt[tid] = 0; }
    __syncthreads();
    const int wave = tid >> 6, lane = tid & 63;
    const size_t row = (size_t)blockIdx.x * 4 + wave;
    const float* xr = x + row * 128;
    float a0 = xr[lane], a1 = xr[lane + 64];
    float s = a0 + a1;
#pragma unroll
    for (int off = 32; off > 0; off >>= 1) s += __shfl_xor(s, off);
    float mean = s * (1.f / 128.f);
    float d0 = a0 - mean, d1 = a1 - mean;
    float v = d0 * d0 + d1 * d1;
#pragma unroll
    for (int off = 32; off > 0; off >>= 1) v += __shfl_xor(v, off);
    float inv = rsqrtf(v * (1.f / 128.f) + 1e-5f);
    float o0 = d0 * inv * g[lane] + b[lane];
    float o1 = d1 * inv * g[lane + 64] + b[lane + 64];
    zbf[row * 128 + lane]      = __float2bfloat16(o0);
    zbf[row * 128 + lane + 64] = __float2bfloat16(o1);
    // router logits: lg[e] = sum_d z[d]*gW[d][e]
    float4 gA = *(const float4*)&gW[lane * 8];
    float4 gB = *(const float4*)&gW[lane * 8 + 4];
    float4 gC = *(const float4*)&gW[(lane + 64) * 8];
    float4 gD = *(const float4*)&gW[(lane + 64) * 8 + 4];
    float lg[8];
    lg[0] = o0 * gA.x + o1 * gC.x;  lg[1] = o0 * gA.y + o1 * gC.y;
    lg[2] = o0 * gA.z + o1 * gC.z;  lg[3] = o0 * gA.w + o1 * gC.w;
    lg[4] = o0 * gB.x + o1 * gD.x;  lg[5] = o0 * gB.y + o1 * gD.y;
    lg[6] = o0 * gB.z + o1 * gD.z;  lg[7] = o0 * gB.w + o1 * gD.w;
#pragma unroll
    for (int e = 0; e < 8; ++e)
#pragma unroll
        for (int off = 32; off > 0; off >>= 1) lg[e] += __shfl_xor(lg[e], off);
    if (lane == 0) {
        float p[8];
        float mx = lg[0];
#pragma unroll
        for (int k = 1; k < 8; ++k) mx = fmaxf(mx, lg[k]);
        float ssum = 0.f;
#pragma unroll
        for (int k = 0; k < 8; ++k) { p[k] = expf(lg[k] - mx); ssum += p[k]; }
        float pinv = 1.f / ssum;
#pragma unroll
        for (int k = 0; k < 8; ++k) p[k] *= pinv;
        int i0 = 0; float v0 = p[0];
#pragma unroll
        for (int k = 1; k < 8; ++k) if (p[k] > v0) { v0 = p[k]; i0 = k; }
        int i1 = -1; float v1 = -1.f;
#pragma unroll
        for (int k = 0; k < 8; ++k) if (k != i0 && p[k] > v1) { v1 = p[k]; i1 = k; }
        float wsum = v0 + v1;
        topi[row * 2] = i0;  topi[row * 2 + 1] = i1;
        topw[row * 2] = v0 / wsum;  topw[row * 2 + 1] = v1 / wsum;
#pragma unroll
        for (int k = 0; k < 8; ++k) atomicAdd(&simp[k], p[k]);
        atomicAdd(&scnt[i0], 1); atomicAdd(&scnt[i1], 1);
    }
    __syncthreads();
    if (tid < 8) {
        int slot = (blockIdx.x & 63) * 8 + tid;
        atomicAdd(&impS[slot], simp[tid]);
        atomicAdd(&cntS[slot], scnt[tid]);
    }
}

// ---------------------------------------------------------------------------
// 7. Sum 64-way-spread counts, 128-aligned scan, counts for bounds check,
//    fill init (= moff), aux-loss accumulation. Single thread; 512 L2 ints.
// ---------------------------------------------------------------------------
__global__ void offsets_kernel(const int* __restrict__ cntS, const float* __restrict__ impS,
                               int* __restrict__ moff, int* __restrict__ fill,
                               float* __restrict__ aux) {
    int c[8]; float im[8];
    for (int e = 0; e < 8; ++e) { c[e] = 0; im[e] = 0.f; }
    for (int sl = 0; sl < 64; ++sl)
        for (int e = 0; e < 8; ++e) { c[e] += cntS[sl * 8 + e]; im[e] += impS[sl * 8 + e]; }
    int t = 0;
    float s = 0.f;
    for (int e = 0; e < 8; ++e) {
        moff[e] = t; fill[e] = t;
        moff[9 + e] = c[e];                       // per-expert count (mode-3 lim)
        t += (c[e] + 127) & ~127;
        s += (im[e] * (1.f / 16384.f)) * ((float)c[e] * (1.f / 16384.f));
    }
    moff[8] = t;
    aux[0] += 8.f * s;
}

// ---------------------------------------------------------------------------
// 8. Scatter tokens into expert-contiguous slots — LDS-aggregated atomics.
// ---------------------------------------------------------------------------
__global__ __launch_bounds__(256) void scatter_kernel(const int* __restrict__ topi,
                                                      const float* __restrict__ topw,
                                                      int* __restrict__ fill, int* __restrict__ atok,
                                                      float* __restrict__ awt, int* __restrict__ tokpos) {
    __shared__ int lcnt[8];
    __shared__ int lbase[8];
    const int tid = threadIdx.x;
    const int token = blockIdx.x * 256 + tid;
    if (tid < 8) lcnt[tid] = 0;
    __syncthreads();
    const int e0 = topi[token * 2], e1 = topi[token * 2 + 1];
    const float w0 = topw[token * 2], w1 = topw[token * 2 + 1];
    const int l0 = atomicAdd(&lcnt[e0], 1);
    const int l1 = atomicAdd(&lcnt[e1], 1);     // e1 != e0 (top-2 distinct)
    __syncthreads();
    if (tid < 8) lbase[tid] = atomicAdd(&fill[tid], lcnt[tid]);
    __syncthreads();
    const int p0 = lbase[e0] + l0;
    const int p1 = lbase[e1] + l1;
    atok[p0] = token;  awt[p0] = w0;  tokpos[token * 2]     = p0;
    atok[p1] = token;  awt[p1] = w1;  tokpos[token * 2 + 1] = p1;
}

// ---------------------------------------------------------------------------
// 9. Fused combine + next-layer LN1: h += expert outputs; optional LN -> zbf
// ---------------------------------------------------------------------------
__global__ __launch_bounds__(256) void combine_ln_kernel(
    const float* __restrict__ yw, const int* __restrict__ tokpos,
    float* __restrict__ h, const float* __restrict__ g, const float* __restrict__ b,
    __hip_bfloat16* __restrict__ zbf)
{
    const int tid = threadIdx.x;
    const int wave = tid >> 6, lane = tid & 63;
    const size_t row = (size_t)blockIdx.x * 4 + wave;
    const int p0 = tokpos[row * 2], p1 = tokpos[row * 2 + 1];
    float a0 = h[row * 128 + lane]      + yw[(size_t)p0 * 128 + lane]
             + yw[(size_t)p1 * 128 + lane];
    float a1 = h[row * 128 + lane + 64] + yw[(size_t)p0 * 128 + lane + 64]
             + yw[(size_t)p1 * 128 + lane + 64];
    h[row * 128 + lane]      = a0;
    h[row * 128 + lane + 64] = a1;
    if (zbf) {
        float s = a0 + a1;
#pragma unroll
        for (int off = 32; off > 0; off >>= 1) s += __shfl_xor(s, off);
        float mean = s * (1.f / 128.f);
        float d0 = a0 - mean, d1 = a1 - mean;
        float v = d0 * d0 + d1 * d1;
#pragma unroll
        for (int off = 32; off > 0; off >>= 1) v += __shfl_xor(v, off);
        float inv = rsqrtf(v * (1.f / 128.f) + 1e-5f);
        zbf[row * 128 + lane]      = __float2bfloat16(d0 * inv * g[lane] + b[lane]);
        zbf[row * 128 + lane + 64] = __float2bfloat16(d1 * inv * g[lane + 64] + b[lane + 64]);
    }
}

// ---------------------------------------------------------------------------
// 10. mean over T -> LN -> head matmul [128,2]; writes aux scalar
// ---------------------------------------------------------------------------
__global__ __launch_bounds__(128) void head_kernel(const float* __restrict__ h,
                                                   const float* __restrict__ g,
                                                   const float* __restrict__ bb,
                                                   const float* __restrict__ hW,
                                                   const float* __restrict__ hb,
                                                   const float* __restrict__ aux,
                                                   float* __restrict__ out) {
    __shared__ float red[128];
    __shared__ float pl[128];
    int b = blockIdx.x, tid = threadIdx.x;
    float s = 0.f;
    for (int t = 0; t < 512; ++t) s += h[((size_t)b * 512 + t) * 128 + tid];
    float pooled = s * (1.f / 512.f);
    red[tid] = pooled; __syncthreads();
    for (int st = 64; st > 0; st >>= 1) { if (tid < st) red[tid] += red[tid + st]; __syncthreads(); }
    float mean = red[0] * (1.f / 128.f);
    __syncthreads();
    float d = pooled - mean;
    red[tid] = d * d; __syncthreads();
    for (int st = 64; st > 0; st >>= 1) { if (tid < st) red[tid] += red[tid + st]; __syncthreads(); }
    float var = red[0] * (1.f / 128.f);
    float ln = d / sqrtf(var + 1e-5f) * g[tid] + bb[tid];
    pl[tid] = ln; __syncthreads();
    if (tid < 2) {
        float acc = hb[tid];
        for (int k = 0; k < 128; ++k) acc += pl[k] * hW[k * 2 + tid];
        out[b * 2 + tid] = acc;
    }
    if (b == 0 && tid == 0) out[64] = aux[0];
}

// ---------------------------------------------------------------------------
extern "C" void kernel_launch(void* const* d_in, const int* in_sizes, int n_in,
                              void* d_out, int out_size, void* d_ws, size_t ws_size,
                              hipStream_t stream) {
    (void)in_sizes; (void)n_in; (void)out_size; (void)ws_size;
    const float* x      = (const float*)d_in[0];
    const float* proj_W = (const float*)d_in[1];
    const float* proj_b = (const float*)d_in[2];
    const float* pos    = (const float*)d_in[3];
    const float* ln1_g  = (const float*)d_in[4];
    const float* ln1_b  = (const float*)d_in[5];
    const float* qkv_W  = (const float*)d_in[6];
    const float* qkv_b  = (const float*)d_in[7];
    const float* out_W  = (const float*)d_in[8];
    const float* out_b  = (const float*)d_in[9];
    const float* ln2_g  = (const float*)d_in[10];
    const float* ln2_b  = (const float*)d_in[11];
    const float* gate_W = (const float*)d_in[12];
    const float* w1     = (const float*)d_in[13];
    const float* b1     = (const float*)d_in[14];
    const float* w2     = (const float*)d_in[15];
    const float* b2     = (const float*)d_in[16];
    const float* hl_g   = (const float*)d_in[17];
    const float* hl_b   = (const float*)d_in[18];
    const float* head_W = (const float*)d_in[19];
    const float* head_b = (const float*)d_in[20];
    float* outp = (float*)d_out;

    // workspace layout (float granularity)
    float* ws = (float*)d_ws;
    size_t off = 0;
    auto alloc = [&](size_t n) { float* p = ws + off; off += (n + 63) & ~(size_t)63; return p; };
    float* hidbf_f = alloc((size_t)MAXASSIGN * 256);  // bf16 hid; aliases xtb
    float* h       = alloc((size_t)BT * 128);
    float* zbf_f   = alloc((size_t)(BT + 1) * 64);    // bf16 [16385][128], row BT = zeros
    float* qkvbf_f = alloc((size_t)BT * 192);         // bf16 [16384][384]
    float* obbf_f  = alloc((size_t)BT * 64);          // bf16 [16384][128]
    float* yw      = alloc((size_t)MAXASSIGN * 128);  // f32
    float* projWt_f= alloc(128 * 448 / 2);
    float* qkvWt_f = alloc(4 * 384 * 128 / 2);
    float* outWt_f = alloc(4 * 128 * 128 / 2);
    float* w1t_f   = alloc((size_t)32 * 512 * 128 / 2);
    float* w2t_f   = alloc((size_t)32 * 128 * 512 / 2);
    float* topw    = alloc(32768);
    float* awt     = alloc(MAXASSIGN);
    float* impc    = alloc(1024);                     // impS[64][8] f32 + cntS[64][8] i32
    float* auxp    = alloc(1);
    int* topi      = (int*)alloc(32768);
    int* atok      = (int*)alloc(MAXASSIGN);
    int* tokpos    = (int*)alloc(32768);
    int* moff      = (int*)alloc(32);
    int* fill      = (int*)alloc(8);
    float* impS    = impc;
    int*   cntS    = (int*)(impc + 512);

    __hip_bfloat16* hidbf  = (__hip_bfloat16*)hidbf_f;
    __hip_bfloat16* xtb    = (__hip_bfloat16*)hidbf_f;   // alias: dead after proj
    __hip_bfloat16* zbf    = (__hip_bfloat16*)zbf_f;
    __hip_bfloat16* qkvbf  = (__hip_bfloat16*)qkvbf_f;
    __hip_bfloat16* obbf   = (__hip_bfloat16*)obbf_f;
    __hip_bfloat16* projWt = (__hip_bfloat16*)projWt_f;
    __hip_bfloat16* qkvWt  = (__hip_bfloat16*)qkvWt_f;
    __hip_bfloat16* outWt  = (__hip_bfloat16*)outWt_f;
    __hip_bfloat16* w1t    = (__hip_bfloat16*)w1t_f;
    __hip_bfloat16* w2t    = (__hip_bfloat16*)w2t_f;

    hipMemsetAsync(auxp, 0, 4, stream);
    hipMemsetAsync((char*)zbf + (size_t)BT * 256, 0, 256, stream);   // zero gather row

    // input transpose + weight conversion (once per call)
    transpose_kernel<<<28672, 256, 0, stream>>>(x, xtb);
    projconv_kernel<<<224, 256, 0, stream>>>(proj_W, projWt);
    wconv_kernel<<<768, 256, 0, stream>>>(qkv_W, qkvWt, 128, 384, 4 * 128 * 384);
    wconv_kernel<<<256, 256, 0, stream>>>(out_W, outWt, 128, 128, 4 * 128 * 128);
    wconv_kernel<<<8192, 256, 0, stream>>>(w1, w1t, 128, 512, 32 * 128 * 512);
    wconv_kernel<<<8192, 256, 0, stream>>>(w2, w2t, 512, 128, 32 * 512 * 128);

    // proj: h = xtb @ projWt^T + proj_b + pos  (K=448)
    mm_kernel<<<dim3(128, 1), 256, 0, stream>>>(xtb, projWt, proj_b, pos, h,
                                                448, 128, 0, 0, nullptr, nullptr, nullptr);
    // layer-0 ln1 (subsequent ln1's are fused into combine_ln)
    ln_kernel<<<4096, 256, 0, stream>>>(h, ln1_g, ln1_b, zbf);

    for (int i = 0; i < 4; ++i) {
        // qkv -> bf16, Q pre-scaled (mode 5)
        mm_kernel<<<dim3(128, 3), 256, 0, stream>>>(zbf, qkvWt + (size_t)i * 384 * 128,
                                                    qkv_b + i * 384, nullptr, qkvbf,
                                                    128, 384, 5, 0, nullptr, nullptr, nullptr);
        attn_kernel<<<dim3(2, 8, 32), 512, 0, stream>>>(qkvbf, obbf);
        mm_kernel<<<dim3(128, 1), 256, 0, stream>>>(obbf, outWt + (size_t)i * 128 * 128,
                                                    out_b + i * 128, h, h,
                                                    128, 128, 2, 0, nullptr, nullptr, nullptr);
        hipMemsetAsync(impc, 0, 4096, stream);
        ln2gate_kernel<<<4096, 256, 0, stream>>>(h, ln2_g + i * 128, ln2_b + i * 128,
                                                 gate_W + (size_t)i * 128 * 8, zbf,
                                                 topi, topw, impS, cntS);
        offsets_kernel<<<1, 1, 0, stream>>>(cntS, impS, moff, fill, auxp);
        scatter_kernel<<<64, 256, 0, stream>>>(topi, topw, fill, atok, awt, tokpos);
        // moe1: hid = gelu(gather(zbf) @ w1t^T + b1)  -> bf16
        mm_kernel<<<dim3(264, 4), 256, 0, stream>>>(zbf, w1t + (size_t)i * 8 * 512 * 128,
                                                    b1 + (size_t)i * 8 * 512, nullptr, hidbf,
                                                    128, 512, 3, 512 * 128, moff, atok, awt);
        // moe2: yw = (hid @ w2t^T + b2) * awt  -> f32
        mm_kernel<<<dim3(264, 1), 256, 0, stream>>>(hidbf, w2t + (size_t)i * 8 * 128 * 512,
                                                    b2 + (size_t)i * 8 * 128, nullptr, yw,
                                                    512, 128, 4, 128 * 512, moff, atok, awt);
        // combine + next-layer ln1 (fused); last layer: no LN
        combine_ln_kernel<<<4096, 256, 0, stream>>>(yw, tokpos, h,
                                                    ln1_g + (i + 1 < 4 ? (i + 1) * 128 : 0),
                                                    ln1_b + (i + 1 < 4 ? (i + 1) * 128 : 0),
                                                    (i < 3) ? zbf : (__hip_bfloat16*)nullptr);
    }
    head_kernel<<<32, 128, 0, stream>>>(h, hl_g, hl_b, head_W, head_b, auxp, outp);
}